// Round 5
// baseline (20049.269 us; speedup 1.0000x reference)
//
#include <hip/hip_runtime.h>
#include <math.h>

#define NN 4096
#define KK 8
#define DD 512
#define HH 512
#define TPB 512
#define MAXR 1024
#define NNHH ((size_t)NN * HH)
#define NGRP 16

typedef float v2f __attribute__((ext_vector_type(2)));

// ws layout (bytes)
#define OFF_CTRL 0                          // barrier control lines (16 KB)
#define OFF_STATE 16384                     // int state[NN]  0=pending 1=active 2=done
#define OFF_CNT   (OFF_STATE + 4 * NN)      // int cntArr[MAXR]
#define OFF_RLEN  (OFF_CNT + 4 * MAXR)      // int rlenArr[MAXR]
#define OFF_LIST0 (OFF_RLEN + 4 * MAXR)     // int list0[NN] (packed i|lenL<<12|lenR<<16)
#define OFF_LIST1 (OFF_LIST0 + 4 * NN)      // int list1[NN]
#define OFF_XIDX  (OFF_LIST1 + 4 * NN)      // int xidx[2][9][NN]
#define OFF_H     (OFF_XIDX + 4 * 2 * 9 * NN)   // float hbuf[2][2][NN][HH] (parity, side)
#define OFF_C     (OFF_H + 4 * 2 * 2 * NN * HH) // float cbuf[2][NN][HH]
#define WS_ZERO_BYTES OFF_LIST0

__device__ __forceinline__ float sigm(float x) { return 1.0f / (1.0f + __expf(-x)); }

// Two-level grid barrier (r4-proven: 70ms -> 20ms vs single-counter).
// Arrivals spread over 16 cache-line-separated group counters, 16 leaders
// hit the root, release fans out via per-group gen flags. Gen is monotonic.
// Spin polls are RELAXED (ACQUIRE polls invalidate the XCD L2 every
// iteration — chip-wide cache poison). One release fence on entry, one
// acquire fence on exit.
__device__ __forceinline__ void grid_barrier(int* ctrl, int grp, int grpsz, int target) {
    __syncthreads();
    if (threadIdx.x == 0) {
        __builtin_amdgcn_fence(__ATOMIC_RELEASE, "agent");
        int* root_cnt = ctrl;            // line 0
        int* root_gen = ctrl + 64;       // line 1
        int* gcnt = ctrl + 128 + grp * 64;
        int* ggen = ctrl + 2048 + grp * 64;
        const int a = __hip_atomic_fetch_add(gcnt, 1, __ATOMIC_RELAXED, __HIP_MEMORY_SCOPE_AGENT);
        if (a == grpsz - 1) {
            __hip_atomic_store(gcnt, 0, __ATOMIC_RELAXED, __HIP_MEMORY_SCOPE_AGENT);
            const int aa = __hip_atomic_fetch_add(root_cnt, 1, __ATOMIC_RELAXED, __HIP_MEMORY_SCOPE_AGENT);
            if (aa == NGRP - 1) {
                __hip_atomic_store(root_cnt, 0, __ATOMIC_RELAXED, __HIP_MEMORY_SCOPE_AGENT);
                __hip_atomic_store(root_gen, target, __ATOMIC_RELEASE, __HIP_MEMORY_SCOPE_AGENT);
            } else {
                while (__hip_atomic_load(root_gen, __ATOMIC_RELAXED, __HIP_MEMORY_SCOPE_AGENT) != target)
                    __builtin_amdgcn_s_sleep(2);
            }
            __hip_atomic_store(ggen, target, __ATOMIC_RELEASE, __HIP_MEMORY_SCOPE_AGENT);
        } else {
            while (__hip_atomic_load(ggen, __ATOMIC_RELAXED, __HIP_MEMORY_SCOPE_AGENT) != target)
                __builtin_amdgcn_s_sleep(2);
        }
        __builtin_amdgcn_fence(__ATOMIC_ACQUIRE, "agent");
    }
    __syncthreads();
}

// launch_bounds(512,2): VGPR cap 256. r3 proved cap=128 makes the allocator
// collapse (64 VGPR + scratch spill -> 52 GB HBM). Weight hoist MUST stay
// in registers; co-residency at NB=512 is checked at launch time instead.
__global__ void __launch_bounds__(TPB, 2)
tree_lstm_kernel(const float* __restrict__ x0,
                 const float* __restrict__ Wl_ih, const float* __restrict__ Wl_hh,
                 const float* __restrict__ bl_ih, const float* __restrict__ bl_hh,
                 const float* __restrict__ Wr_ih, const float* __restrict__ Wr_hh,
                 const float* __restrict__ br_ih, const float* __restrict__ br_hh,
                 const float* __restrict__ W_enc, const float* __restrict__ b_enc,
                 const int* __restrict__ lch, const int* __restrict__ rch,
                 float* ctx, char* ws, int nb) {
    const int tid  = threadIdx.x;
    const int gtid = blockIdx.x * TPB + tid;
    const int wave = gtid >> 6;        // 0..(nb*8-1)
    const int lane = tid & 63;
    const int u    = wave & 511;       // hidden unit owned by this wave
    const int side = (wave >> 9) & 1;  // 0 = left chain, 1 = right chain
    const int p    = wave >> 10;       // slot split id (0..pcnt-1)
    const int egrp = wave >> 9;        // enc slot split id (0..ecnt-1)
    const int pcnt = (nb * (TPB / 64)) >> 10;  // 2 (nb=256) or 4 (nb=512)
    const int ecnt = (nb * (TPB / 64)) >> 9;   // 4 or 8
    const int bgrp = blockIdx.x & (NGRP - 1);
    const int grpsz = nb / NGRP;

    int*   ctrl    = (int*)(ws + OFF_CTRL);
    int*   state   = (int*)(ws + OFF_STATE);
    int*   cntArr  = (int*)(ws + OFF_CNT);
    int*   rlenArr = (int*)(ws + OFF_RLEN);
    int*   list0   = (int*)(ws + OFF_LIST0);
    int*   list1   = (int*)(ws + OFF_LIST1);
    int*   xidx    = (int*)(ws + OFF_XIDX);
    float* hbuf    = (float*)(ws + OFF_H);
    float* cbuf    = (float*)(ws + OFF_C);

    const float* Wih = side ? Wr_ih : Wl_ih;
    const float* Whh = side ? Wr_hh : Wl_hh;
    const float* bih = side ? br_ih : bl_ih;
    const float* bhh = side ? br_hh : bl_hh;

    // Wave-resident weights as float2 pairs (v_pk_fma_f32 targets).
    // Lane l covers cols [8l, 8l+8). Gate order i,f,g,o.
    v2f wih2[4][4], whh2[4][4];
    float bsum[4];
#pragma unroll
    for (int g = 0; g < 4; ++g) {
        const size_t row = (size_t)g * HH + u;
        const float4 wa = *(const float4*)(Wih + row * DD + lane * 8);
        const float4 wb = *(const float4*)(Wih + row * DD + lane * 8 + 4);
        wih2[g][0] = (v2f){wa.x, wa.y}; wih2[g][1] = (v2f){wa.z, wa.w};
        wih2[g][2] = (v2f){wb.x, wb.y}; wih2[g][3] = (v2f){wb.z, wb.w};
        const float4 ha = *(const float4*)(Whh + row * HH + lane * 8);
        const float4 hb = *(const float4*)(Whh + row * HH + lane * 8 + 4);
        whh2[g][0] = (v2f){ha.x, ha.y}; whh2[g][1] = (v2f){ha.z, ha.w};
        whh2[g][2] = (v2f){hb.x, hb.y}; whh2[g][3] = (v2f){hb.z, hb.w};
        bsum[g] = bih[row] + bhh[row];
    }
    v2f wenc2[8];
#pragma unroll
    for (int j = 0; j < 4; ++j) {
        const float4 t = *(const float4*)(W_enc + (size_t)u * (2 * HH) + lane * 16 + j * 4);
        wenc2[j * 2 + 0] = (v2f){t.x, t.y};
        wenc2[j * 2 + 1] = (v2f){t.z, t.w};
    }
    const float bencv = b_enc[u];

    int r = 0, doneSum = 0, bnum = 0;
    while (doneSum < NN && r < MAXR - 2) {
        int* curList = (r & 1) ? list1 : list0;

        // phase A: activate nodes whose children are all done; precompute
        // per-substep input rows so the hot loop has no pointer chase.
        if (gtid < NN) {
            const int i = gtid;
            if (state[i] == 0) {
                bool ok = true;
                int ll = 1, lr = 1;
#pragma unroll
                for (int k = 0; k < KK; ++k) {
                    const int c = lch[i * KK + k];
                    if (c >= 0) { ll = k + 2; if (state[c] != 2) ok = false; }
                }
#pragma unroll
                for (int k = 0; k < KK; ++k) {
                    const int c = rch[i * KK + k];
                    if (c >= 0) { lr = k + 2; if (state[c] != 2) ok = false; }
                }
                if (ok) {
                    state[i] = 1;
                    const int pos = atomicAdd(&cntArr[r], 1);
                    curList[pos] = i | (ll << 12) | (lr << 16);
                    atomicMax(&rlenArr[r], ll > lr ? ll : lr);
                    xidx[(0 * 9 + 0) * NN + pos] = i;
                    xidx[(1 * 9 + 0) * NN + pos] = i;
#pragma unroll
                    for (int q = 1; q < 9; ++q) {
                        xidx[(0 * 9 + q) * NN + pos] = (q < ll) ? lch[i * KK + q - 1] : -1;
                        xidx[(1 * 9 + q) * NN + pos] = (q < lr) ? rch[i * KK + q - 1] : -1;
                    }
                }
            }
        }
        grid_barrier(ctrl, bgrp, grpsz, ++bnum);
        const int B = __hip_atomic_load(&cntArr[r], __ATOMIC_RELAXED, __HIP_MEMORY_SCOPE_AGENT);
        const int L = __hip_atomic_load(&rlenArr[r], __ATOMIC_RELAXED, __HIP_MEMORY_SCOPE_AGENT);
        doneSum += B;

        // lockstep chain sub-steps; h double-buffered by step parity
        for (int q = 0; q < L; ++q) {
            float*       hb_w = hbuf + (size_t)((q & 1) * 2 + side) * NNHH;
            const float* hb_r = hbuf + (size_t)(((q & 1) ^ 1) * 2 + side) * NNHH;
            float*       cb   = cbuf + (size_t)side * NNHH;
            const int*   xq   = xidx + (size_t)(side * 9 + q) * NN;
            const float* xbase = (q == 0) ? x0 : ctx;
            for (int s0 = p * 4; s0 < B; s0 += pcnt * 4) {
                const int4 e4 = *(const int4*)(curList + s0);  // independent loads
                const int4 c4 = *(const int4*)(xq + s0);
                const int ei[4] = {e4.x, e4.y, e4.z, e4.w};
                const int ci[4] = {c4.x, c4.y, c4.z, c4.w};
                bool act[4];
                v2f  xr2[4][4], hr2[4][4];
                float cp[4];
#pragma unroll
                for (int k = 0; k < 4; ++k)
                    act[k] = (s0 + k < B) && (ci[k] >= 0);
                // gather phase
#pragma unroll
                for (int k = 0; k < 4; ++k) {
                    if (!act[k]) continue;
                    const float* xv = xbase + (size_t)ci[k] * DD + lane * 8;
                    const float4 xa = *(const float4*)xv;
                    const float4 xb = *(const float4*)(xv + 4);
                    xr2[k][0] = (v2f){xa.x, xa.y}; xr2[k][1] = (v2f){xa.z, xa.w};
                    xr2[k][2] = (v2f){xb.x, xb.y}; xr2[k][3] = (v2f){xb.z, xb.w};
                    if (q > 0) {
                        const int i = ei[k] & 0xFFF;
                        const float* hv = hb_r + (size_t)i * HH + lane * 8;
                        const float4 hA = *(const float4*)hv;
                        const float4 hB = *(const float4*)(hv + 4);
                        hr2[k][0] = (v2f){hA.x, hA.y}; hr2[k][1] = (v2f){hA.z, hA.w};
                        hr2[k][2] = (v2f){hB.x, hB.y}; hr2[k][3] = (v2f){hB.z, hB.w};
                        cp[k] = cb[(size_t)i * HH + u];
                    } else cp[k] = 0.f;
                }
                // compute phase: 4 independent packed-FMA + reduce chains
#pragma unroll
                for (int k = 0; k < 4; ++k) {
                    if (!act[k]) continue;
                    const int i = ei[k] & 0xFFF;
                    v2f A0 = {0.f, 0.f}, A1 = {0.f, 0.f}, A2 = {0.f, 0.f}, A3 = {0.f, 0.f};
#pragma unroll
                    for (int j = 0; j < 4; ++j) {
                        A0 += wih2[0][j] * xr2[k][j];
                        A1 += wih2[1][j] * xr2[k][j];
                        A2 += wih2[2][j] * xr2[k][j];
                        A3 += wih2[3][j] * xr2[k][j];
                    }
                    if (q > 0) {
#pragma unroll
                        for (int j = 0; j < 4; ++j) {
                            A0 += whh2[0][j] * hr2[k][j];
                            A1 += whh2[1][j] * hr2[k][j];
                            A2 += whh2[2][j] * hr2[k][j];
                            A3 += whh2[3][j] * hr2[k][j];
                        }
                    }
                    float a0 = A0[0] + A0[1], a1 = A1[0] + A1[1];
                    float a2 = A2[0] + A2[1], a3 = A3[0] + A3[1];
                    // merge butterfly: lane l ends holding gate (l&3)'s sum
                    float v01, v23, v;
                    {
                        const bool hi = lane & 1;
                        float keep = hi ? a1 : a0, send = hi ? a0 : a1;
                        v01 = keep + __shfl_xor(send, 1, 64);
                        keep = hi ? a3 : a2; send = hi ? a2 : a3;
                        v23 = keep + __shfl_xor(send, 1, 64);
                    }
                    {
                        const bool hi = lane & 2;
                        const float keep = hi ? v23 : v01, send = hi ? v01 : v23;
                        v = keep + __shfl_xor(send, 2, 64);
                    }
                    v += __shfl_xor(v, 4, 64);
                    v += __shfl_xor(v, 8, 64);
                    v += __shfl_xor(v, 16, 64);
                    v += __shfl_xor(v, 32, 64);
                    const float g1 = __shfl(v, 1, 64);
                    const float g2 = __shfl(v, 2, 64);
                    const float g3 = __shfl(v, 3, 64);
                    // valid on lane 0 (v there = gate i)
                    const float gi = v  + bsum[0];
                    const float gf = g1 + bsum[1];
                    const float gg = g2 + bsum[2];
                    const float go = g3 + bsum[3];
                    const float cn = sigm(gf) * cp[k] + sigm(gi) * tanhf(gg);
                    const float hn = sigm(go) * tanhf(cn);
                    if (lane == 0) {
                        cb[(size_t)i * HH + u]   = cn;
                        hb_w[(size_t)i * HH + u] = hn;
                    }
                }
            }
            grid_barrier(ctrl, bgrp, grpsz, ++bnum);
        }

        // enc: ctx[i][u] = tanh(W_enc[u] . [hl|hr] + b_enc[u]); per-side parity
        if (B > 0) {
            const int lhalf = lane >> 5;          // 0 -> hl, 1 -> hr
            const int col   = (lane * 16) & 511;
            for (int slot = egrp; slot < B; slot += ecnt) {
                const int e   = curList[slot];
                const int i   = e & 0xFFF;
                const int len = (e >> (12 + 4 * lhalf)) & 0xF;
                const float* hv = hbuf + (size_t)(((len - 1) & 1) * 2 + lhalf) * NNHH
                                + (size_t)i * HH + col;
                v2f acc2 = {0.f, 0.f};
#pragma unroll
                for (int j = 0; j < 4; ++j) {
                    const float4 t = *(const float4*)(hv + j * 4);
                    acc2 += wenc2[j * 2 + 0] * (v2f){t.x, t.y};
                    acc2 += wenc2[j * 2 + 1] * (v2f){t.z, t.w};
                }
                float acc = acc2[0] + acc2[1];
#pragma unroll
                for (int m = 1; m < 64; m <<= 1) acc += __shfl_xor(acc, m, 64);
                if (lane == 0) {
                    ctx[(size_t)i * DD + u] = tanhf(acc + bencv);
                    if (u == 0) state[i] = 2;   // node done; visible next round
                }
            }
        }
        grid_barrier(ctrl, bgrp, grpsz, ++bnum);
        ++r;
    }
}

extern "C" void kernel_launch(void* const* d_in, const int* in_sizes, int n_in,
                              void* d_out, int out_size, void* d_ws, size_t ws_size,
                              hipStream_t stream) {
    // Co-residency guard: NB=512 needs 2 blocks/CU, i.e. VGPR <= 128.
    // If the allocator drifted above that, fall back to the safe 1-block/CU
    // grid instead of deadlocking the grid barrier.
    int nb = 256;
    hipFuncAttributes attr;
    if (hipFuncGetAttributes(&attr, (const void*)tree_lstm_kernel) == hipSuccess &&
        attr.numRegs > 0 && attr.numRegs <= 128) {
        nb = 512;
    }
    hipMemsetAsync(d_ws, 0, WS_ZERO_BYTES, stream);
    tree_lstm_kernel<<<dim3(nb), dim3(TPB), 0, stream>>>(
        (const float*)d_in[0],
        (const float*)d_in[1], (const float*)d_in[2],
        (const float*)d_in[3], (const float*)d_in[4],
        (const float*)d_in[5], (const float*)d_in[6],
        (const float*)d_in[7], (const float*)d_in[8],
        (const float*)d_in[9], (const float*)d_in[10],
        (const int*)d_in[11], (const int*)d_in[12],
        (float*)d_out, (char*)d_ws, nb);
}